// Round 2
// baseline (819.043 us; speedup 1.0000x reference)
//
#include <hip/hip_runtime.h>
#include <hip/hip_bf16.h>

#define DI __device__ __forceinline__

typedef short bf16x8 __attribute__((ext_vector_type(8)));
typedef float f32x4 __attribute__((ext_vector_type(4)));

typedef __attribute__((address_space(3))) unsigned lds_u32;
typedef __attribute__((address_space(1))) const unsigned g_u32;

DI void gload16(const void* g, void* lds) {
  __builtin_amdgcn_global_load_lds((g_u32*)g, (lds_u32*)lds, 16, 0, 0);
}

// ---------------------------------------------------------------------------
// Weight transpose: W[K][N] fp32 -> Wt[N][K] bf16 (tiled via LDS)
// ---------------------------------------------------------------------------
__global__ __launch_bounds__(256)
void wtrans_kernel(const float* __restrict__ w, __hip_bfloat16* __restrict__ wt,
                   int K, int N) {
  __shared__ float tile[32][33];
  const int nb = blockIdx.x * 32, kb = blockIdx.y * 32;
  const int tx = threadIdx.x & 31, ty = threadIdx.x >> 5;  // 32 x 8
#pragma unroll
  for (int i = 0; i < 4; ++i)
    tile[ty + i * 8][tx] = w[(size_t)(kb + ty + i * 8) * N + nb + tx];
  __syncthreads();
#pragma unroll
  for (int i = 0; i < 4; ++i)
    wt[(size_t)(nb + ty + i * 8) * K + kb + tx] = __float2bfloat16(tile[tx][ty + i * 8]);
}

// ---------------------------------------------------------------------------
// RoPE cos/sin tables: [576][64] each
// ---------------------------------------------------------------------------
__global__ void tables_kernel(float* __restrict__ cost, float* __restrict__ sint) {
  const int s = blockIdx.x;    // 0..575
  const int d = threadIdx.x;   // 0..63
  const int j = d >> 1;
  const float pos = (j < 16) ? (float)(s % 24) * (1.0f / 3.0f)
                             : (float)(s / 24) * (1.0f / 3.0f);
  const int fi = j & 15;
  const float freq = powf(10000.0f, -(float)fi * (1.0f / 16.0f));
  const float a = pos * freq;
  cost[s * 64 + d] = cosf(a);
  sint[s * 64 + d] = sinf(a);
}

// ---------------------------------------------------------------------------
// LayerNorm: fp32 in -> bf16 out, one block per token (1024 ch, 256 thr x 4)
// ---------------------------------------------------------------------------
__global__ __launch_bounds__(256)
void ln_kernel(const float* __restrict__ in, const float* __restrict__ g,
               const float* __restrict__ b, __hip_bfloat16* __restrict__ out) {
  const int t = blockIdx.x, tid = threadIdx.x;
  const float4 x = *(const float4*)(in + (size_t)t * 1024 + tid * 4);
  float s = x.x + x.y + x.z + x.w;
  float sq = x.x * x.x + x.y * x.y + x.z * x.z + x.w * x.w;
#pragma unroll
  for (int off = 32; off >= 1; off >>= 1) {
    s += __shfl_down(s, off);
    sq += __shfl_down(sq, off);
  }
  __shared__ float red[8];
  const int wave = tid >> 6, lane = tid & 63;
  if (lane == 0) { red[wave] = s; red[4 + wave] = sq; }
  __syncthreads();
  s = red[0] + red[1] + red[2] + red[3];
  sq = red[4] + red[5] + red[6] + red[7];
  const float mean = s * (1.0f / 1024.0f);
  const float var = sq * (1.0f / 1024.0f) - mean * mean;
  const float rstd = rsqrtf(var + 1e-6f);
  const int c = tid * 4;
  const float4 gg = *(const float4*)(g + c);
  const float4 bb = *(const float4*)(b + c);
  __hip_bfloat16* o = out + (size_t)t * 1024 + c;
  o[0] = __float2bfloat16((x.x - mean) * rstd * gg.x + bb.x);
  o[1] = __float2bfloat16((x.y - mean) * rstd * gg.y + bb.y);
  o[2] = __float2bfloat16((x.z - mean) * rstd * gg.z + bb.z);
  o[3] = __float2bfloat16((x.w - mean) * rstd * gg.w + bb.w);
}

// ---------------------------------------------------------------------------
// 256x256 8-phase GEMM (m201-style template, plain HIP).
// C[M,N] = A[M,K] @ Bt[N,K]^T, bf16 in, fp32 accum.
// 512 thr = 8 waves (2M x 4N), per-wave 128x64 out, BK=64, 2-deep pipeline.
// Counted vmcnt(8) at tile top (never 0 mid-loop); raw s_barrier; per-phase
// {ds_read frags -> barrier -> lgkmcnt(0) -> setprio1 -> 16 MFMA -> setprio0
//  -> barrier}; stage(t+2) after tile's last barrier (buffer dead).
// T2 bank-conflict fix: gload_lds writes linearly, global SOURCE granule is
// XORed with row&7; reads apply the same XOR -> uniform 8 touches/bank.
// Tail: A buffers padded to 256-multiple rows; stores predicated gm<M.
// MODE 0: out bf16 = acc + bias    MODE 1: out bf16 = gelu(acc + bias)
// ---------------------------------------------------------------------------
template<int MODE>
__global__ __launch_bounds__(512, 2)
void gemm256_kernel(const __hip_bfloat16* __restrict__ A,
                    const __hip_bfloat16* __restrict__ Bt,
                    const float* __restrict__ bias,
                    __hip_bfloat16* __restrict__ out,
                    int M, int N, int K) {
  __shared__ __hip_bfloat16 As[2][256 * 64];
  __shared__ __hip_bfloat16 Bs[2][256 * 64];
  const int tid = threadIdx.x;
  const int wave = tid >> 6, lane = tid & 63;
  const int lr = lane & 15, lg = lane >> 4;
  const int wr = wave >> 2, wc = wave & 3;  // 2 x 4 wave grid
  // bijective XCD swizzle (m204 variant, works for nwg % 8 != 0)
  const unsigned nwg = gridDim.x * gridDim.y;
  const unsigned bid0 = blockIdx.y * gridDim.x + blockIdx.x;
  const unsigned xcd = bid0 & 7u, idx = bid0 >> 3;
  const unsigned q8 = nwg >> 3, r8 = nwg & 7u;
  const unsigned L = (xcd < r8 ? xcd * (q8 + 1u)
                               : r8 * (q8 + 1u) + (xcd - r8) * q8) + idx;
  const int bm = (int)(L / gridDim.x) * 256;
  const int bn = (int)(L % gridDim.x) * 256;

  const int srow8 = lane >> 3, sgr = lane & 7;
  const int scol = (sgr ^ srow8) << 3;  // swizzled source col (elements)

  auto stage = [&](int buf, int k0) {
#pragma unroll
    for (int l = 0; l < 4; ++l) {
      const int c = l * 8 + wave;  // 8-row chunk, wave-uniform LDS base
      gload16(A + (size_t)(bm + c * 8 + srow8) * K + k0 + scol,
              &As[buf][c * 512]);
    }
#pragma unroll
    for (int l = 0; l < 4; ++l) {
      const int c = l * 8 + wave;
      gload16(Bt + (size_t)(bn + c * 8 + srow8) * K + k0 + scol,
              &Bs[buf][c * 512]);
    }
  };

  f32x4 acc[8][4] = {};
  const int nk = K >> 6;

  stage(0, 0);
  stage(1, 64);

  for (int t = 0; t < nk; ++t) {
    const int cur = t & 1;
    if (t + 1 < nk) {
      asm volatile("s_waitcnt vmcnt(8)" ::: "memory");  // t landed, t+1 flying
    } else {
      asm volatile("s_waitcnt vmcnt(0)" ::: "memory");  // last tile: drain
    }
    __builtin_amdgcn_sched_barrier(0);
    __builtin_amdgcn_s_barrier();  // all waves' stages for tile t landed

    bf16x8 bfr[4];
#pragma unroll
    for (int ph = 0; ph < 4; ++ph) {
      const int kh = ph >> 1, mh = ph & 1;  // B frags reused across mh pair
      if (mh == 0) {
#pragma unroll
        for (int ni = 0; ni < 4; ++ni) {
          const int r = wc * 64 + ni * 16 + lr;
          const int pg = ((kh << 2) + lg) ^ (lr & 7);
          bfr[ni] = *(const bf16x8*)&Bs[cur][r * 64 + pg * 8];
        }
      }
      bf16x8 af[4];
#pragma unroll
      for (int mi = 0; mi < 4; ++mi) {
        const int r = wr * 128 + mh * 64 + mi * 16 + lr;
        const int pg = ((kh << 2) + lg) ^ (lr & 7);
        af[mi] = *(const bf16x8*)&As[cur][r * 64 + pg * 8];
      }
      __builtin_amdgcn_s_barrier();
      asm volatile("s_waitcnt lgkmcnt(0)" ::: "memory");
      __builtin_amdgcn_sched_barrier(0);  // rule #18: fence MFMA below wait
      __builtin_amdgcn_s_setprio(1);
#pragma unroll
      for (int mi = 0; mi < 4; ++mi)
#pragma unroll
        for (int ni = 0; ni < 4; ++ni)
          acc[mh * 4 + mi][ni] = __builtin_amdgcn_mfma_f32_16x16x32_bf16(
              af[mi], bfr[ni], acc[mh * 4 + mi][ni], 0, 0, 0);
      __builtin_amdgcn_s_setprio(0);
      __builtin_amdgcn_s_barrier();
    }
    // buf[cur] fully consumed by all waves (last barrier above) -> overwrite
    if (t + 2 < nk) stage(cur, (t + 2) << 6);
    __builtin_amdgcn_sched_barrier(0);
  }

#pragma unroll
  for (int ni = 0; ni < 4; ++ni) {
    const int gn = bn + wc * 64 + ni * 16 + lr;
    const float bv = bias ? bias[gn] : 0.0f;
#pragma unroll
    for (int mi = 0; mi < 8; ++mi) {
      const int rowb = bm + wr * 128 + mi * 16 + lg * 4;
#pragma unroll
      for (int j = 0; j < 4; ++j) {
        const int gm = rowb + j;
        if (gm < M) {
          float v = acc[mi][ni][j] + bv;
          if (MODE == 1) v = 0.5f * v * (1.0f + erff(v * 0.70710678f));
          out[(size_t)gm * N + gn] = __float2bfloat16(v);
        }
      }
    }
  }
}

// ---------------------------------------------------------------------------
// 128x128 GEMM (round-0 single-buffer body + XCD swizzle) for N=1024 GEMMs.
// MODE 2: out f32 += acc + bias
// MODE 3: window-unpartition row perm; out f32[t] = resid[t] + acc + bias
// ---------------------------------------------------------------------------
template<int MODE>
__global__ __launch_bounds__(256)
void gemm_bt_kernel(const __hip_bfloat16* __restrict__ A,
                    const __hip_bfloat16* __restrict__ Bt,
                    const float* __restrict__ bias,
                    void* __restrict__ out,
                    const float* __restrict__ resid,
                    int M, int N, int K) {
  __shared__ __hip_bfloat16 As[128 * 64];
  __shared__ __hip_bfloat16 Bs[128 * 64];
  const int tid = threadIdx.x;
  const int wave = tid >> 6, lane = tid & 63;
  const int lr = lane & 15, lg = lane >> 4;
  const unsigned nwg = gridDim.x * gridDim.y;
  const unsigned bid0 = blockIdx.y * gridDim.x + blockIdx.x;
  const unsigned xcd = bid0 & 7u, idx = bid0 >> 3;
  const unsigned q8 = nwg >> 3, r8 = nwg & 7u;
  const unsigned L = (xcd < r8 ? xcd * (q8 + 1u)
                               : r8 * (q8 + 1u) + (xcd - r8) * q8) + idx;
  const int bm = (int)(L / gridDim.x) * 128;
  const int bn = (int)(L % gridDim.x) * 128;
  const int wr = (wave >> 1) * 64, wc = (wave & 1) * 64;
  const int srow = lane >> 3, scol = (lane & 7) * 8;

  f32x4 acc[4][4] = {};

  for (int k0 = 0; k0 < K; k0 += 64) {
#pragma unroll
    for (int c = 0; c < 4; ++c) {
      const int ch = wave * 4 + c;
      gload16(A + (size_t)(bm + ch * 8 + srow) * K + k0 + scol, &As[ch * 512]);
      gload16(Bt + (size_t)(bn + ch * 8 + srow) * K + k0 + scol, &Bs[ch * 512]);
    }
    __syncthreads();
#pragma unroll
    for (int kk = 0; kk < 64; kk += 32) {
      bf16x8 af[4], bfr[4];
#pragma unroll
      for (int i = 0; i < 4; ++i)
        af[i] = *(const bf16x8*)&As[(wr + i * 16 + lr) * 64 + kk + lg * 8];
#pragma unroll
      for (int i = 0; i < 4; ++i)
        bfr[i] = *(const bf16x8*)&Bs[(wc + i * 16 + lr) * 64 + kk + lg * 8];
#pragma unroll
      for (int mi = 0; mi < 4; ++mi)
#pragma unroll
        for (int ni = 0; ni < 4; ++ni)
          acc[mi][ni] = __builtin_amdgcn_mfma_f32_16x16x32_bf16(af[mi], bfr[ni],
                                                                acc[mi][ni], 0, 0, 0);
    }
    __syncthreads();
  }

#pragma unroll
  for (int ni = 0; ni < 4; ++ni) {
    const int gn = bn + wc + ni * 16 + lr;
    const float bv = bias ? bias[gn] : 0.0f;
#pragma unroll
    for (int mi = 0; mi < 4; ++mi) {
      const int rowb = bm + wr + mi * 16 + lg * 4;
#pragma unroll
      for (int j = 0; j < 4; ++j) {
        const float v = acc[mi][ni][j] + bv;
        const int gm = rowb + j;
        if (MODE == 2) {
          ((float*)out)[(size_t)gm * N + gn] += v;
        } else {
          const int win = gm / 576, s = gm % 576;
          const int bb2 = win / 9, wi = (win % 9) / 3, wj = win % 3;
          const int t = (bb2 * 72 + wi * 24 + (s / 24)) * 72 + wj * 24 + (s % 24);
          ((float*)out)[(size_t)t * 1024 + gn] =
              resid[(size_t)t * 1024 + gn] + v;
        }
      }
    }
  }
}

// ---------------------------------------------------------------------------
// RoPE + bias + window scatter for Q (pre-scaled by 0.125) and K.
// ---------------------------------------------------------------------------
__global__ __launch_bounds__(256)
void rope_kernel(const __hip_bfloat16* __restrict__ qkvraw,
                 const float* __restrict__ bq, const float* __restrict__ bk,
                 const float* __restrict__ cost, const float* __restrict__ sint,
                 __hip_bfloat16* __restrict__ qw, __hip_bfloat16* __restrict__ kw) {
  const int s = blockIdx.x;    // 0..575
  const int win = blockIdx.y;  // 0..17
  const int b = win / 9, wi = (win % 9) / 3, wj = win % 3;
  const int t = (b * 72 + wi * 24 + (s / 24)) * 72 + wj * 24 + (s % 24);
  const int tid = threadIdx.x;
  const int col = tid * 4;           // 0..1020, aligned pairs
  const int head = col >> 6, d = col & 63;
  const float c0 = cost[s * 64 + d + 0], c1 = cost[s * 64 + d + 1];
  const float c2 = cost[s * 64 + d + 2], c3 = cost[s * 64 + d + 3];
  const float s0 = sint[s * 64 + d + 0], s1 = sint[s * 64 + d + 1];
  const float s2 = sint[s * 64 + d + 2], s3 = sint[s * 64 + d + 3];
  const size_t rbase = (size_t)t * 3072;
  const size_t obase = (((size_t)(win * 16 + head)) * 576 + s) * 64 + d;
  {  // Q (fold softmax scale 1/8)
    const float q0 = __bfloat162float(qkvraw[rbase + col + 0]) + bq[col + 0];
    const float q1 = __bfloat162float(qkvraw[rbase + col + 1]) + bq[col + 1];
    const float q2 = __bfloat162float(qkvraw[rbase + col + 2]) + bq[col + 2];
    const float q3 = __bfloat162float(qkvraw[rbase + col + 3]) + bq[col + 3];
    qw[obase + 0] = __float2bfloat16(0.125f * (q0 * c0 - q1 * s0));
    qw[obase + 1] = __float2bfloat16(0.125f * (q1 * c1 + q0 * s1));
    qw[obase + 2] = __float2bfloat16(0.125f * (q2 * c2 - q3 * s2));
    qw[obase + 3] = __float2bfloat16(0.125f * (q3 * c3 + q2 * s3));
  }
  {  // K
    const float k0 = __bfloat162float(qkvraw[rbase + 1024 + col + 0]) + bk[col + 0];
    const float k1 = __bfloat162float(qkvraw[rbase + 1024 + col + 1]) + bk[col + 1];
    const float k2 = __bfloat162float(qkvraw[rbase + 1024 + col + 2]) + bk[col + 2];
    const float k3 = __bfloat162float(qkvraw[rbase + 1024 + col + 3]) + bk[col + 3];
    kw[obase + 0] = __float2bfloat16(k0 * c0 - k1 * s0);
    kw[obase + 1] = __float2bfloat16(k1 * c1 + k0 * s1);
    kw[obase + 2] = __float2bfloat16(k2 * c2 - k3 * s2);
    kw[obase + 3] = __float2bfloat16(k3 * c3 + k2 * s3);
  }
}

// ---------------------------------------------------------------------------
// V: bias + window gather + transpose: vt[win][head][d][s] bf16 (for PV MFMA)
// ---------------------------------------------------------------------------
__global__ __launch_bounds__(256)
void vtrans_kernel(const __hip_bfloat16* __restrict__ qkvraw,
                   const float* __restrict__ bv,
                   __hip_bfloat16* __restrict__ vt) {
  const int head = blockIdx.x, win = blockIdx.y;
  const int b = win / 9, wi = (win % 9) / 3, wj = win % 3;
  __shared__ __hip_bfloat16 tile[64][72];
  const int tid = threadIdx.x;
  for (int s0 = 0; s0 < 576; s0 += 64) {
#pragma unroll
    for (int rep = 0; rep < 16; ++rep) {
      const int e = rep * 256 + tid;  // 0..4095
      const int si = e >> 6, d = e & 63;
      const int s = s0 + si;
      const int t = (b * 72 + wi * 24 + (s / 24)) * 72 + wj * 24 + (s % 24);
      const float v = __bfloat162float(qkvraw[(size_t)t * 3072 + 2048 + head * 64 + d])
                    + bv[head * 64 + d];
      tile[d][si] = __float2bfloat16(v);
    }
    __syncthreads();
#pragma unroll
    for (int rep = 0; rep < 16; ++rep) {
      const int e = rep * 256 + tid;
      const int d = e >> 6, si = e & 63;
      vt[((size_t)(win * 16 + head) * 64 + d) * 576 + s0 + si] = tile[d][si];
    }
    __syncthreads();
  }
}

// ---------------------------------------------------------------------------
// Flash attention per (qtile, head, win). 256 thr = 4 waves, 16 q-rows/wave.
// ---------------------------------------------------------------------------
__global__ __launch_bounds__(256)
void attn_kernel(const __hip_bfloat16* __restrict__ qw,
                 const __hip_bfloat16* __restrict__ kw,
                 const __hip_bfloat16* __restrict__ vt,
                 __hip_bfloat16* __restrict__ ow) {
  __shared__ __hip_bfloat16 Klds[2][64 * 64];
  __shared__ __hip_bfloat16 Vlds[2][64 * 64];
  __shared__ __hip_bfloat16 Plds[4 * 16 * 64];
  const unsigned nwg = gridDim.x * gridDim.y * gridDim.z;
  const unsigned bid0 = (blockIdx.z * gridDim.y + blockIdx.y) * gridDim.x + blockIdx.x;
  const unsigned Lw = (bid0 & 7u) * (nwg >> 3) + (bid0 >> 3);
  const int qt = (int)(Lw % 9u);          // 0..8
  const unsigned r = Lw / 9u;
  const int head = (int)(r & 15u);        // 0..15
  const int win = (int)(r >> 4);          // 0..17
  const int bh = win * 16 + head;
  const int tid = threadIdx.x, wave = tid >> 6, lane = tid & 63;
  const int lr = lane & 15, lg = lane >> 4;

  const int qrow = qt * 64 + wave * 16 + lr;
  const __hip_bfloat16* qbase = qw + ((size_t)bh * 576 + qrow) * 64;
  const bf16x8 q0 = *(const bf16x8*)(qbase + lg * 8);
  const bf16x8 q1 = *(const bf16x8*)(qbase + 32 + lg * 8);

  f32x4 oacc[4] = {};
  float mrow[4] = {-1e30f, -1e30f, -1e30f, -1e30f};
  float lrow[4] = {};

  auto stagekv = [&](int buf, int kv) {
#pragma unroll
    for (int c = 0; c < 2; ++c) {
      const int ch = wave * 2 + c;
      gload16(kw + ((size_t)bh * 576 + kv * 64 + ch * 8 + (lane >> 3)) * 64 + (lane & 7) * 8,
              &Klds[buf][ch * 512]);
      gload16(vt + ((size_t)bh * 64 + ch * 8 + (lane >> 3)) * 576 + kv * 64 + (lane & 7) * 8,
              &Vlds[buf][ch * 512]);
    }
  };

  stagekv(0, 0);
  __syncthreads();

  for (int kv = 0; kv < 9; ++kv) {
    const int cur = kv & 1;
    if (kv + 1 < 9) stagekv(cur ^ 1, kv + 1);
    __builtin_amdgcn_sched_barrier(0);

    f32x4 sfr[4];
#pragma unroll
    for (int c = 0; c < 4; ++c) {
      const bf16x8 b0 = *(const bf16x8*)&Klds[cur][(c * 16 + lr) * 64 + lg * 8];
      const bf16x8 b1 = *(const bf16x8*)&Klds[cur][(c * 16 + lr) * 64 + 32 + lg * 8];
      f32x4 z = {};
      z = __builtin_amdgcn_mfma_f32_16x16x32_bf16(q0, b0, z, 0, 0, 0);
      z = __builtin_amdgcn_mfma_f32_16x16x32_bf16(q1, b1, z, 0, 0, 0);
      sfr[c] = z;
    }

    float p[4][4], rscale[4];
#pragma unroll
    for (int j = 0; j < 4; ++j) {
      float mj = fmaxf(fmaxf(sfr[0][j], sfr[1][j]), fmaxf(sfr[2][j], sfr[3][j]));
#pragma unroll
      for (int off = 1; off < 16; off <<= 1) mj = fmaxf(mj, __shfl_xor(mj, off));
      const float mn = fmaxf(mrow[j], mj);
      rscale[j] = __expf(mrow[j] - mn);
      mrow[j] = mn;
      float rs = 0.0f;
#pragma unroll
      for (int c = 0; c < 4; ++c) {
        const float pp = __expf(sfr[c][j] - mn);
        p[c][j] = pp;
        rs += pp;
      }
#pragma unroll
      for (int off = 1; off < 16; off <<= 1) rs += __shfl_xor(rs, off);
      lrow[j] = lrow[j] * rscale[j] + rs;
    }
#pragma unroll
    for (int d = 0; d < 4; ++d)
#pragma unroll
      for (int j = 0; j < 4; ++j) oacc[d][j] *= rscale[j];

#pragma unroll
    for (int c = 0; c < 4; ++c)
#pragma unroll
      for (int j = 0; j < 4; ++j)
        Plds[wave * 1024 + (lg * 4 + j) * 64 + c * 16 + lr] = __float2bfloat16(p[c][j]);

    const bf16x8 pa0 = *(const bf16x8*)&Plds[wave * 1024 + lr * 64 + lg * 8];
    const bf16x8 pa1 = *(const bf16x8*)&Plds[wave * 1024 + lr * 64 + 32 + lg * 8];
#pragma unroll
    for (int d = 0; d < 4; ++d) {
      const bf16x8 v0 = *(const bf16x8*)&Vlds[cur][(d * 16 + lr) * 64 + lg * 8];
      const bf16x8 v1 = *(const bf16x8*)&Vlds[cur][(d * 16 + lr) * 64 + 32 + lg * 8];
      oacc[d] = __builtin_amdgcn_mfma_f32_16x16x32_bf16(pa0, v0, oacc[d], 0, 0, 0);
      oacc[d] = __builtin_amdgcn_mfma_f32_16x16x32_bf16(pa1, v1, oacc[d], 0, 0, 0);
    }
    __syncthreads();
  }

#pragma unroll
  for (int j = 0; j < 4; ++j) {
    const float inv = 1.0f / lrow[j];
    const int srow = qt * 64 + wave * 16 + lg * 4 + j;
    const size_t base = ((size_t)win * 576 + srow) * 1024 + head * 64;
#pragma unroll
    for (int d = 0; d < 4; ++d)
      ow[base + d * 16 + lr] = __float2bfloat16(oacc[d][j] * inv);
  }
}

// ---------------------------------------------------------------------------
extern "C" void kernel_launch(void* const* d_in, const int* in_sizes, int n_in,
                              void* d_out, int out_size, void* d_ws, size_t ws_size,
                              hipStream_t stream) {
  const float* hidden = (const float*)d_in[0];
  const float* ln1_g = (const float*)d_in[1];
  const float* ln1_b = (const float*)d_in[2];
  const float* wq = (const float*)d_in[3];
  const float* bq = (const float*)d_in[4];
  const float* wk = (const float*)d_in[5];
  const float* bk = (const float*)d_in[6];
  const float* wv = (const float*)d_in[7];
  const float* bv = (const float*)d_in[8];
  const float* wo = (const float*)d_in[9];
  const float* bo = (const float*)d_in[10];
  const float* ln2_g = (const float*)d_in[11];
  const float* ln2_b = (const float*)d_in[12];
  const float* w1 = (const float*)d_in[13];
  const float* b1 = (const float*)d_in[14];
  const float* w2 = (const float*)d_in[15];
  const float* b2 = (const float*)d_in[16];
  float* out = (float*)d_out;

  char* p = (char*)d_ws;
  auto alloc = [&](size_t bytes) {
    char* r = p;
    p += (bytes + 255) & ~(size_t)255;
    return r;
  };
  __hip_bfloat16* wt_qkv = (__hip_bfloat16*)alloc(3072ull * 1024 * 2);
  __hip_bfloat16* wt_wo  = (__hip_bfloat16*)alloc(1024ull * 1024 * 2);
  __hip_bfloat16* wt_w1  = (__hip_bfloat16*)alloc(4096ull * 1024 * 2);
  __hip_bfloat16* wt_w2  = (__hip_bfloat16*)alloc(1024ull * 4096 * 2);
  float* cost = (float*)alloc(576ull * 64 * 4);
  float* sint = (float*)alloc(576ull * 64 * 4);
  // xbuf padded to 10496 rows (256-multiple) for 256-row GEMM tiles; pad rows
  // hold garbage, outputs for gm >= 10368 are predicated off.
  __hip_bfloat16* xbuf = (__hip_bfloat16*)alloc(10496ull * 1024 * 2);
  char* big = alloc(10368ull * 4096 * 2);  // qkvraw+qw | h1
  __hip_bfloat16* qkvraw = (__hip_bfloat16*)big;
  __hip_bfloat16* qw = (__hip_bfloat16*)(big + 10368ull * 3072 * 2);
  __hip_bfloat16* h1 = (__hip_bfloat16*)big;
  __hip_bfloat16* kw = (__hip_bfloat16*)alloc(18ull * 16 * 576 * 64 * 2);
  __hip_bfloat16* vt = (__hip_bfloat16*)alloc(18ull * 16 * 64 * 576 * 2);

  // weights -> bf16 transposed
  wtrans_kernel<<<dim3(32, 32), 256, 0, stream>>>(wq, wt_qkv, 1024, 1024);
  wtrans_kernel<<<dim3(32, 32), 256, 0, stream>>>(wk, wt_qkv + 1024ull * 1024, 1024, 1024);
  wtrans_kernel<<<dim3(32, 32), 256, 0, stream>>>(wv, wt_qkv + 2048ull * 1024, 1024, 1024);
  wtrans_kernel<<<dim3(32, 32), 256, 0, stream>>>(wo, wt_wo, 1024, 1024);
  wtrans_kernel<<<dim3(128, 32), 256, 0, stream>>>(w1, wt_w1, 1024, 4096);
  wtrans_kernel<<<dim3(32, 128), 256, 0, stream>>>(w2, wt_w2, 4096, 1024);
  tables_kernel<<<576, 64, 0, stream>>>(cost, sint);

  // LN1 -> xln (bf16)
  ln_kernel<<<10368, 256, 0, stream>>>(hidden, ln1_g, ln1_b, xbuf);
  // QKV fused GEMM (256x256 8-phase): [10368,1024] x [3072,1024]^T -> qkvraw
  gemm256_kernel<0><<<dim3(12, 41), 512, 0, stream>>>(
      xbuf, wt_qkv, nullptr, qkvraw, 10368, 3072, 1024);
  // RoPE + window scatter (q scaled by 0.125); V bias + transpose
  rope_kernel<<<dim3(576, 18), 256, 0, stream>>>(qkvraw, bq, bk, cost, sint, qw, kw);
  vtrans_kernel<<<dim3(16, 18), 256, 0, stream>>>(qkvraw, bv, vt);
  // attention -> o_w (windowed rows, [tw][1024]) into xbuf
  attn_kernel<<<dim3(9, 16, 18), 256, 0, stream>>>(qw, kw, vt, xbuf);
  // Wo GEMM + bias + residual + window-unpartition -> d_out (fp32 x)
  gemm_bt_kernel<3><<<dim3(8, 81), 256, 0, stream>>>(
      xbuf, wt_wo, bo, out, hidden, 10368, 1024, 1024);
  // LN2 -> xln2 (bf16)
  ln_kernel<<<10368, 256, 0, stream>>>(out, ln2_g, ln2_b, xbuf);
  // MLP up + GELU (256x256 8-phase) -> h1 bf16
  gemm256_kernel<1><<<dim3(16, 41), 512, 0, stream>>>(
      xbuf, wt_w1, b1, h1, 10368, 4096, 1024);
  // MLP down, += into d_out
  gemm_bt_kernel<2><<<dim3(8, 81), 256, 0, stream>>>(
      h1, wt_w2, b2, out, nullptr, 10368, 1024, 4096);
}

// Round 3
// 775.496 us; speedup vs baseline: 1.0562x; 1.0562x over previous
//
#include <hip/hip_runtime.h>
#include <hip/hip_bf16.h>

#define DI __device__ __forceinline__

typedef short bf16x8 __attribute__((ext_vector_type(8)));
typedef float f32x4 __attribute__((ext_vector_type(4)));

typedef __attribute__((address_space(3))) unsigned lds_u32;
typedef __attribute__((address_space(1))) const unsigned g_u32;

DI void gload16(const void* g, void* lds) {
  __builtin_amdgcn_global_load_lds((g_u32*)g, (lds_u32*)lds, 16, 0, 0);
}

// ---------------------------------------------------------------------------
// Weight transpose: W[K][N] fp32 -> Wt[N][K] bf16 (tiled via LDS)
// ---------------------------------------------------------------------------
__global__ __launch_bounds__(256)
void wtrans_kernel(const float* __restrict__ w, __hip_bfloat16* __restrict__ wt,
                   int K, int N) {
  __shared__ float tile[32][33];
  const int nb = blockIdx.x * 32, kb = blockIdx.y * 32;
  const int tx = threadIdx.x & 31, ty = threadIdx.x >> 5;  // 32 x 8
#pragma unroll
  for (int i = 0; i < 4; ++i)
    tile[ty + i * 8][tx] = w[(size_t)(kb + ty + i * 8) * N + nb + tx];
  __syncthreads();
#pragma unroll
  for (int i = 0; i < 4; ++i)
    wt[(size_t)(nb + ty + i * 8) * K + kb + tx] = __float2bfloat16(tile[tx][ty + i * 8]);
}

// ---------------------------------------------------------------------------
// RoPE cos/sin tables: [576][64] each
// ---------------------------------------------------------------------------
__global__ void tables_kernel(float* __restrict__ cost, float* __restrict__ sint) {
  const int s = blockIdx.x;    // 0..575
  const int d = threadIdx.x;   // 0..63
  const int j = d >> 1;
  const float pos = (j < 16) ? (float)(s % 24) * (1.0f / 3.0f)
                             : (float)(s / 24) * (1.0f / 3.0f);
  const int fi = j & 15;
  const float freq = powf(10000.0f, -(float)fi * (1.0f / 16.0f));
  const float a = pos * freq;
  cost[s * 64 + d] = cosf(a);
  sint[s * 64 + d] = sinf(a);
}

// ---------------------------------------------------------------------------
// LayerNorm: fp32 in -> bf16 out, one block per token (1024 ch, 256 thr x 4)
// ---------------------------------------------------------------------------
__global__ __launch_bounds__(256)
void ln_kernel(const float* __restrict__ in, const float* __restrict__ g,
               const float* __restrict__ b, __hip_bfloat16* __restrict__ out) {
  const int t = blockIdx.x, tid = threadIdx.x;
  const float4 x = *(const float4*)(in + (size_t)t * 1024 + tid * 4);
  float s = x.x + x.y + x.z + x.w;
  float sq = x.x * x.x + x.y * x.y + x.z * x.z + x.w * x.w;
#pragma unroll
  for (int off = 32; off >= 1; off >>= 1) {
    s += __shfl_down(s, off);
    sq += __shfl_down(sq, off);
  }
  __shared__ float red[8];
  const int wave = tid >> 6, lane = tid & 63;
  if (lane == 0) { red[wave] = s; red[4 + wave] = sq; }
  __syncthreads();
  s = red[0] + red[1] + red[2] + red[3];
  sq = red[4] + red[5] + red[6] + red[7];
  const float mean = s * (1.0f / 1024.0f);
  const float var = sq * (1.0f / 1024.0f) - mean * mean;
  const float rstd = rsqrtf(var + 1e-6f);
  const int c = tid * 4;
  const float4 gg = *(const float4*)(g + c);
  const float4 bb = *(const float4*)(b + c);
  __hip_bfloat16* o = out + (size_t)t * 1024 + c;
  o[0] = __float2bfloat16((x.x - mean) * rstd * gg.x + bb.x);
  o[1] = __float2bfloat16((x.y - mean) * rstd * gg.y + bb.y);
  o[2] = __float2bfloat16((x.z - mean) * rstd * gg.z + bb.z);
  o[3] = __float2bfloat16((x.w - mean) * rstd * gg.w + bb.w);
}

// ---------------------------------------------------------------------------
// gemm3: 256xBN tile, BK=32, 3-buffer LDS pipeline with 2-tile load lead and
// counted vmcnt (NEVER drains to 0 mid-loop). 512 thr = 8 waves.
//   BN=256: waves 2Mx4N, per-wave 128x64 (MI=8), LDS 96KB, 4 loads/thr/tile
//   BN=128: waves 4Mx2N, per-wave  64x64 (MI=4), LDS 72KB, 3 loads/thr/tile
// Per tile t: wait vmcnt(L) [t landed, t+1 flying] -> barrier ->
//   stage(t+2) into buf[(t+2)%3] (dead since end of t-1) -> ds_read frags ->
//   lgkmcnt(0)+sched_barrier -> setprio1 -> MI*4 MFMA -> setprio0.
// Bank swizzle: 16B granule g at row r stores source granule g^((r>>1)&3);
// stage pre-swizzles the GLOBAL source column, LDS stays linear (m173/m201).
// MODE 0: bf16 = acc + bias     MODE 1: bf16 = gelu(acc + bias)
// MODE 2: f32 += acc + bias     MODE 3: window-unpartition; f32 = resid + acc
// ---------------------------------------------------------------------------
template<int MODE, int BN>
__global__ __launch_bounds__(512, 2)
void gemm3_kernel(const __hip_bfloat16* __restrict__ A,
                  const __hip_bfloat16* __restrict__ Bt,
                  const float* __restrict__ bias,
                  void* __restrict__ out,
                  const float* __restrict__ resid,
                  int M, int N, int K) {
  constexpr int MI = (BN == 256) ? 8 : 4;   // A frags per wave
  constexpr int ACH = 2;                    // A 16-row chunks per wave
  constexpr int BCH = (BN == 256) ? 2 : 1;  // B 16-row chunks per wave
  __shared__ __hip_bfloat16 SA[3 * 256 * 32];
  __shared__ __hip_bfloat16 SB[3 * BN * 32];
  const int tid = threadIdx.x;
  const int wave = tid >> 6, lane = tid & 63;
  const int lr = lane & 15, lg = lane >> 4;
  // bijective XCD swizzle (m204)
  const unsigned nwg = gridDim.x * gridDim.y;
  const unsigned bid0 = blockIdx.y * gridDim.x + blockIdx.x;
  const unsigned xcd = bid0 & 7u, idx = bid0 >> 3;
  const unsigned q8 = nwg >> 3, r8 = nwg & 7u;
  const unsigned L = (xcd < r8 ? xcd * (q8 + 1u)
                               : r8 * (q8 + 1u) + (xcd - r8) * q8) + idx;
  const int bm = (int)(L / gridDim.x) * 256;
  const int bn = (int)(L % gridDim.x) * BN;
  const int wrow = (BN == 256) ? (wave >> 2) * 128 : (wave >> 1) * 64;
  const int wcol = (BN == 256) ? (wave & 3) * 64 : (wave & 1) * 64;

  // staging lanes: 16 rows x 4 granules (16B) per wave-instruction
  const int srow = lane >> 2, sg = lane & 3;
  const int scol = (sg ^ ((srow >> 1) & 3)) << 3;  // pre-swizzled source col
  // fragment read granule (same for every frag row: (r>>1)&3 == (lr>>1)&3)
  const int rg = (lg ^ ((lr >> 1) & 3)) << 3;

  auto stage = [&](int t) {
    const int buf = t % 3;
    const int k0 = t << 5;
#pragma unroll
    for (int l = 0; l < ACH; ++l) {
      const int c = wave * ACH + l;  // 16-row chunk
      gload16(A + (size_t)(bm + c * 16 + srow) * K + k0 + scol,
              &SA[buf * 8192 + c * 512]);
    }
#pragma unroll
    for (int l = 0; l < BCH; ++l) {
      const int c = wave * BCH + l;
      gload16(Bt + (size_t)(bn + c * 16 + srow) * K + k0 + scol,
              &SB[buf * (BN * 32) + c * 512]);
    }
  };

  f32x4 acc[MI][4] = {};
  const int nk = K >> 5;

  stage(0);
  stage(1);

  for (int t = 0; t < nk; ++t) {
    const int buf = t % 3;
    if (t < nk - 1) {
      if constexpr (BN == 256) {
        asm volatile("s_waitcnt vmcnt(4)" ::: "memory");
      } else {
        asm volatile("s_waitcnt vmcnt(3)" ::: "memory");
      }
    } else {
      asm volatile("s_waitcnt vmcnt(0)" ::: "memory");
    }
    __builtin_amdgcn_s_barrier();        // everyone's tile-t chunks landed
    __builtin_amdgcn_sched_barrier(0);   // nothing crosses the barrier upward
    if (t + 2 < nk) stage(t + 2);        // buf[(t+2)%3] dead since end of t-1

    bf16x8 af[MI], bfr[4];
#pragma unroll
    for (int i = 0; i < MI; ++i)
      af[i] = *(const bf16x8*)&SA[buf * 8192 + (wrow + i * 16 + lr) * 32 + rg];
#pragma unroll
    for (int i = 0; i < 4; ++i)
      bfr[i] = *(const bf16x8*)&SB[buf * (BN * 32) + (wcol + i * 16 + lr) * 32 + rg];
    asm volatile("s_waitcnt lgkmcnt(0)" ::: "memory");
    __builtin_amdgcn_sched_barrier(0);   // rule #18: keep MFMA below the wait
    __builtin_amdgcn_s_setprio(1);
#pragma unroll
    for (int mi = 0; mi < MI; ++mi)
#pragma unroll
      for (int ni = 0; ni < 4; ++ni)
        acc[mi][ni] = __builtin_amdgcn_mfma_f32_16x16x32_bf16(
            af[mi], bfr[ni], acc[mi][ni], 0, 0, 0);
    __builtin_amdgcn_s_setprio(0);
  }

#pragma unroll
  for (int ni = 0; ni < 4; ++ni) {
    const int gn = bn + wcol + ni * 16 + lr;
    const float bv = bias ? bias[gn] : 0.0f;
#pragma unroll
    for (int mi = 0; mi < MI; ++mi) {
      const int rowb = bm + wrow + mi * 16 + lg * 4;
#pragma unroll
      for (int j = 0; j < 4; ++j) {
        const int gm = rowb + j;
        if (gm < M) {
          float v = acc[mi][ni][j] + bv;
          if (MODE == 0) {
            ((__hip_bfloat16*)out)[(size_t)gm * N + gn] = __float2bfloat16(v);
          } else if (MODE == 1) {
            const float gl = 0.5f * v * (1.0f + erff(v * 0.70710678f));
            ((__hip_bfloat16*)out)[(size_t)gm * N + gn] = __float2bfloat16(gl);
          } else if (MODE == 2) {
            ((float*)out)[(size_t)gm * N + gn] += v;
          } else {
            const int win = gm / 576, s = gm % 576;
            const int bb2 = win / 9, wi = (win % 9) / 3, wj = win % 3;
            const int t2 = (bb2 * 72 + wi * 24 + (s / 24)) * 72 + wj * 24 + (s % 24);
            ((float*)out)[(size_t)t2 * 1024 + gn] =
                resid[(size_t)t2 * 1024 + gn] + v;
          }
        }
      }
    }
  }
}

// ---------------------------------------------------------------------------
// RoPE + bias + window scatter for Q (pre-scaled by 0.125) and K.
// ---------------------------------------------------------------------------
__global__ __launch_bounds__(256)
void rope_kernel(const __hip_bfloat16* __restrict__ qkvraw,
                 const float* __restrict__ bq, const float* __restrict__ bk,
                 const float* __restrict__ cost, const float* __restrict__ sint,
                 __hip_bfloat16* __restrict__ qw, __hip_bfloat16* __restrict__ kw) {
  const int s = blockIdx.x;    // 0..575
  const int win = blockIdx.y;  // 0..17
  const int b = win / 9, wi = (win % 9) / 3, wj = win % 3;
  const int t = (b * 72 + wi * 24 + (s / 24)) * 72 + wj * 24 + (s % 24);
  const int tid = threadIdx.x;
  const int col = tid * 4;           // 0..1020, aligned pairs
  const int head = col >> 6, d = col & 63;
  const float c0 = cost[s * 64 + d + 0], c1 = cost[s * 64 + d + 1];
  const float c2 = cost[s * 64 + d + 2], c3 = cost[s * 64 + d + 3];
  const float s0 = sint[s * 64 + d + 0], s1 = sint[s * 64 + d + 1];
  const float s2 = sint[s * 64 + d + 2], s3 = sint[s * 64 + d + 3];
  const size_t rbase = (size_t)t * 3072;
  const size_t obase = (((size_t)(win * 16 + head)) * 576 + s) * 64 + d;
  {  // Q (fold softmax scale 1/8)
    const float q0 = __bfloat162float(qkvraw[rbase + col + 0]) + bq[col + 0];
    const float q1 = __bfloat162float(qkvraw[rbase + col + 1]) + bq[col + 1];
    const float q2 = __bfloat162float(qkvraw[rbase + col + 2]) + bq[col + 2];
    const float q3 = __bfloat162float(qkvraw[rbase + col + 3]) + bq[col + 3];
    qw[obase + 0] = __float2bfloat16(0.125f * (q0 * c0 - q1 * s0));
    qw[obase + 1] = __float2bfloat16(0.125f * (q1 * c1 + q0 * s1));
    qw[obase + 2] = __float2bfloat16(0.125f * (q2 * c2 - q3 * s2));
    qw[obase + 3] = __float2bfloat16(0.125f * (q3 * c3 + q2 * s3));
  }
  {  // K
    const float k0 = __bfloat162float(qkvraw[rbase + 1024 + col + 0]) + bk[col + 0];
    const float k1 = __bfloat162float(qkvraw[rbase + 1024 + col + 1]) + bk[col + 1];
    const float k2 = __bfloat162float(qkvraw[rbase + 1024 + col + 2]) + bk[col + 2];
    const float k3 = __bfloat162float(qkvraw[rbase + 1024 + col + 3]) + bk[col + 3];
    kw[obase + 0] = __float2bfloat16(k0 * c0 - k1 * s0);
    kw[obase + 1] = __float2bfloat16(k1 * c1 + k0 * s1);
    kw[obase + 2] = __float2bfloat16(k2 * c2 - k3 * s2);
    kw[obase + 3] = __float2bfloat16(k3 * c3 + k2 * s3);
  }
}

// ---------------------------------------------------------------------------
// V: bias + window gather + transpose: vt[win][head][d][s] bf16 (for PV MFMA)
// ---------------------------------------------------------------------------
__global__ __launch_bounds__(256)
void vtrans_kernel(const __hip_bfloat16* __restrict__ qkvraw,
                   const float* __restrict__ bv,
                   __hip_bfloat16* __restrict__ vt) {
  const int head = blockIdx.x, win = blockIdx.y;
  const int b = win / 9, wi = (win % 9) / 3, wj = win % 3;
  __shared__ __hip_bfloat16 tile[64][72];
  const int tid = threadIdx.x;
  for (int s0 = 0; s0 < 576; s0 += 64) {
#pragma unroll
    for (int rep = 0; rep < 16; ++rep) {
      const int e = rep * 256 + tid;  // 0..4095
      const int si = e >> 6, d = e & 63;
      const int s = s0 + si;
      const int t = (b * 72 + wi * 24 + (s / 24)) * 72 + wj * 24 + (s % 24);
      const float v = __bfloat162float(qkvraw[(size_t)t * 3072 + 2048 + head * 64 + d])
                    + bv[head * 64 + d];
      tile[d][si] = __float2bfloat16(v);
    }
    __syncthreads();
#pragma unroll
    for (int rep = 0; rep < 16; ++rep) {
      const int e = rep * 256 + tid;
      const int d = e >> 6, si = e & 63;
      vt[((size_t)(win * 16 + head) * 64 + d) * 576 + s0 + si] = tile[d][si];
    }
    __syncthreads();
  }
}

// ---------------------------------------------------------------------------
// Flash attention per (qtile, head, win). 256 thr = 4 waves, 16 q-rows/wave.
// ---------------------------------------------------------------------------
__global__ __launch_bounds__(256)
void attn_kernel(const __hip_bfloat16* __restrict__ qw,
                 const __hip_bfloat16* __restrict__ kw,
                 const __hip_bfloat16* __restrict__ vt,
                 __hip_bfloat16* __restrict__ ow) {
  __shared__ __hip_bfloat16 Klds[2][64 * 64];
  __shared__ __hip_bfloat16 Vlds[2][64 * 64];
  __shared__ __hip_bfloat16 Plds[4 * 16 * 64];
  const unsigned nwg = gridDim.x * gridDim.y * gridDim.z;
  const unsigned bid0 = (blockIdx.z * gridDim.y + blockIdx.y) * gridDim.x + blockIdx.x;
  const unsigned Lw = (bid0 & 7u) * (nwg >> 3) + (bid0 >> 3);
  const int qt = (int)(Lw % 9u);          // 0..8
  const unsigned r = Lw / 9u;
  const int head = (int)(r & 15u);        // 0..15
  const int win = (int)(r >> 4);          // 0..17
  const int bh = win * 16 + head;
  const int tid = threadIdx.x, wave = tid >> 6, lane = tid & 63;
  const int lr = lane & 15, lg = lane >> 4;

  const int qrow = qt * 64 + wave * 16 + lr;
  const __hip_bfloat16* qbase = qw + ((size_t)bh * 576 + qrow) * 64;
  const bf16x8 q0 = *(const bf16x8*)(qbase + lg * 8);
  const bf16x8 q1 = *(const bf16x8*)(qbase + 32 + lg * 8);

  f32x4 oacc[4] = {};
  float mrow[4] = {-1e30f, -1e30f, -1e30f, -1e30f};
  float lrow[4] = {};

  auto stagekv = [&](int buf, int kv) {
#pragma unroll
    for (int c = 0; c < 2; ++c) {
      const int ch = wave * 2 + c;
      gload16(kw + ((size_t)bh * 576 + kv * 64 + ch * 8 + (lane >> 3)) * 64 + (lane & 7) * 8,
              &Klds[buf][ch * 512]);
      gload16(vt + ((size_t)bh * 64 + ch * 8 + (lane >> 3)) * 576 + kv * 64 + (lane & 7) * 8,
              &Vlds[buf][ch * 512]);
    }
  };

  stagekv(0, 0);
  __syncthreads();

  for (int kv = 0; kv < 9; ++kv) {
    const int cur = kv & 1;
    if (kv + 1 < 9) stagekv(cur ^ 1, kv + 1);
    __builtin_amdgcn_sched_barrier(0);

    f32x4 sfr[4];
#pragma unroll
    for (int c = 0; c < 4; ++c) {
      const bf16x8 b0 = *(const bf16x8*)&Klds[cur][(c * 16 + lr) * 64 + lg * 8];
      const bf16x8 b1 = *(const bf16x8*)&Klds[cur][(c * 16 + lr) * 64 + 32 + lg * 8];
      f32x4 z = {};
      z = __builtin_amdgcn_mfma_f32_16x16x32_bf16(q0, b0, z, 0, 0, 0);
      z = __builtin_amdgcn_mfma_f32_16x16x32_bf16(q1, b1, z, 0, 0, 0);
      sfr[c] = z;
    }

    float p[4][4], rscale[4];
#pragma unroll
    for (int j = 0; j < 4; ++j) {
      float mj = fmaxf(fmaxf(sfr[0][j], sfr[1][j]), fmaxf(sfr[2][j], sfr[3][j]));
#pragma unroll
      for (int off = 1; off < 16; off <<= 1) mj = fmaxf(mj, __shfl_xor(mj, off));
      const float mn = fmaxf(mrow[j], mj);
      rscale[j] = __expf(mrow[j] - mn);
      mrow[j] = mn;
      float rs = 0.0f;
#pragma unroll
      for (int c = 0; c < 4; ++c) {
        const float pp = __expf(sfr[c][j] - mn);
        p[c][j] = pp;
        rs += pp;
      }
#pragma unroll
      for (int off = 1; off < 16; off <<= 1) rs += __shfl_xor(rs, off);
      lrow[j] = lrow[j] * rscale[j] + rs;
    }
#pragma unroll
    for (int d = 0; d < 4; ++d)
#pragma unroll
      for (int j = 0; j < 4; ++j) oacc[d][j] *= rscale[j];

#pragma unroll
    for (int c = 0; c < 4; ++c)
#pragma unroll
      for (int j = 0; j < 4; ++j)
        Plds[wave * 1024 + (lg * 4 + j) * 64 + c * 16 + lr] = __float2bfloat16(p[c][j]);

    const bf16x8 pa0 = *(const bf16x8*)&Plds[wave * 1024 + lr * 64 + lg * 8];
    const bf16x8 pa1 = *(const bf16x8*)&Plds[wave * 1024 + lr * 64 + 32 + lg * 8];
#pragma unroll
    for (int d = 0; d < 4; ++d) {
      const bf16x8 v0 = *(const bf16x8*)&Vlds[cur][(d * 16 + lr) * 64 + lg * 8];
      const bf16x8 v1 = *(const bf16x8*)&Vlds[cur][(d * 16 + lr) * 64 + 32 + lg * 8];
      oacc[d] = __builtin_amdgcn_mfma_f32_16x16x32_bf16(pa0, v0, oacc[d], 0, 0, 0);
      oacc[d] = __builtin_amdgcn_mfma_f32_16x16x32_bf16(pa1, v1, oacc[d], 0, 0, 0);
    }
    __syncthreads();
  }

#pragma unroll
  for (int j = 0; j < 4; ++j) {
    const float inv = 1.0f / lrow[j];
    const int srow = qt * 64 + wave * 16 + lg * 4 + j;
    const size_t base = ((size_t)win * 576 + srow) * 1024 + head * 64;
#pragma unroll
    for (int d = 0; d < 4; ++d)
      ow[base + d * 16 + lr] = __float2bfloat16(oacc[d][j] * inv);
  }
}

// ---------------------------------------------------------------------------
extern "C" void kernel_launch(void* const* d_in, const int* in_sizes, int n_in,
                              void* d_out, int out_size, void* d_ws, size_t ws_size,
                              hipStream_t stream) {
  const float* hidden = (const float*)d_in[0];
  const float* ln1_g = (const float*)d_in[1];
  const float* ln1_b = (const float*)d_in[2];
  const float* wq = (const float*)d_in[3];
  const float* bq = (const float*)d_in[4];
  const float* wk = (const float*)d_in[5];
  const float* bk = (const float*)d_in[6];
  const float* wv = (const float*)d_in[7];
  const float* bv = (const float*)d_in[8];
  const float* wo = (const float*)d_in[9];
  const float* bo = (const float*)d_in[10];
  const float* ln2_g = (const float*)d_in[11];
  const float* ln2_b = (const float*)d_in[12];
  const float* w1 = (const float*)d_in[13];
  const float* b1 = (const float*)d_in[14];
  const float* w2 = (const float*)d_in[15];
  const float* b2 = (const float*)d_in[16];
  float* out = (float*)d_out;

  char* p = (char*)d_ws;
  auto alloc = [&](size_t bytes) {
    char* r = p;
    p += (bytes + 255) & ~(size_t)255;
    return r;
  };
  __hip_bfloat16* wt_qkv = (__hip_bfloat16*)alloc(3072ull * 1024 * 2);
  __hip_bfloat16* wt_wo  = (__hip_bfloat16*)alloc(1024ull * 1024 * 2);
  __hip_bfloat16* wt_w1  = (__hip_bfloat16*)alloc(4096ull * 1024 * 2);
  __hip_bfloat16* wt_w2  = (__hip_bfloat16*)alloc(1024ull * 4096 * 2);
  float* cost = (float*)alloc(576ull * 64 * 4);
  float* sint = (float*)alloc(576ull * 64 * 4);
  // xbuf padded to 10496 rows (256-multiple); pad rows garbage, outputs for
  // gm >= 10368 predicated off in gemm3 epilogues.
  __hip_bfloat16* xbuf = (__hip_bfloat16*)alloc(10496ull * 1024 * 2);
  char* big = alloc(10496ull * 4096 * 2);  // qkvraw+qw | h1(padded rows)
  __hip_bfloat16* qkvraw = (__hip_bfloat16*)big;
  __hip_bfloat16* qw = (__hip_bfloat16*)(big + 10368ull * 3072 * 2);
  __hip_bfloat16* h1 = (__hip_bfloat16*)big;
  __hip_bfloat16* kw = (__hip_bfloat16*)alloc(18ull * 16 * 576 * 64 * 2);
  __hip_bfloat16* vt = (__hip_bfloat16*)alloc(18ull * 16 * 64 * 576 * 2);

  // weights -> bf16 transposed
  wtrans_kernel<<<dim3(32, 32), 256, 0, stream>>>(wq, wt_qkv, 1024, 1024);
  wtrans_kernel<<<dim3(32, 32), 256, 0, stream>>>(wk, wt_qkv + 1024ull * 1024, 1024, 1024);
  wtrans_kernel<<<dim3(32, 32), 256, 0, stream>>>(wv, wt_qkv + 2048ull * 1024, 1024, 1024);
  wtrans_kernel<<<dim3(32, 32), 256, 0, stream>>>(wo, wt_wo, 1024, 1024);
  wtrans_kernel<<<dim3(128, 32), 256, 0, stream>>>(w1, wt_w1, 1024, 4096);
  wtrans_kernel<<<dim3(32, 128), 256, 0, stream>>>(w2, wt_w2, 4096, 1024);
  tables_kernel<<<576, 64, 0, stream>>>(cost, sint);

  // LN1 -> xln (bf16)
  ln_kernel<<<10368, 256, 0, stream>>>(hidden, ln1_g, ln1_b, xbuf);
  // QKV fused GEMM: [10368,1024] x [3072,1024]^T -> qkvraw bf16
  gemm3_kernel<0, 256><<<dim3(12, 41), 512, 0, stream>>>(
      xbuf, wt_qkv, nullptr, qkvraw, nullptr, 10368, 3072, 1024);
  // RoPE + window scatter (q scaled by 0.125); V bias + transpose
  rope_kernel<<<dim3(576, 18), 256, 0, stream>>>(qkvraw, bq, bk, cost, sint, qw, kw);
  vtrans_kernel<<<dim3(16, 18), 256, 0, stream>>>(qkvraw, bv, vt);
  // attention -> o_w (windowed rows, [tw][1024]) into xbuf
  attn_kernel<<<dim3(9, 16, 18), 256, 0, stream>>>(qw, kw, vt, xbuf);
  // Wo GEMM + bias + residual + window-unpartition -> d_out (fp32 x)
  gemm3_kernel<3, 128><<<dim3(8, 41), 512, 0, stream>>>(
      xbuf, wt_wo, bo, out, hidden, 10368, 1024, 1024);
  // LN2 -> xln2 (bf16)
  ln_kernel<<<10368, 256, 0, stream>>>(out, ln2_g, ln2_b, xbuf);
  // MLP up + GELU -> h1 bf16
  gemm3_kernel<1, 256><<<dim3(16, 41), 512, 0, stream>>>(
      xbuf, wt_w1, b1, h1, nullptr, 10368, 4096, 1024);
  // MLP down, += into d_out
  gemm3_kernel<2, 128><<<dim3(8, 41), 512, 0, stream>>>(
      h1, wt_w2, b2, out, nullptr, 10368, 1024, 4096);
}

// Round 4
// 591.485 us; speedup vs baseline: 1.3847x; 1.3111x over previous
//
#include <hip/hip_runtime.h>
#include <hip/hip_bf16.h>

#define DI __device__ __forceinline__

typedef short bf16x8 __attribute__((ext_vector_type(8)));
typedef float f32x4 __attribute__((ext_vector_type(4)));

typedef __attribute__((address_space(3))) unsigned lds_u32;
typedef __attribute__((address_space(1))) const unsigned g_u32;

DI void gload16(const void* g, void* lds) {
  __builtin_amdgcn_global_load_lds((g_u32*)g, (lds_u32*)lds, 16, 0, 0);
}

DI unsigned short bf16bits(float f) {
  __hip_bfloat16 h = __float2bfloat16(f);
  return *(unsigned short*)&h;
}

// ---------------------------------------------------------------------------
// Weight transpose: W[K][N] fp32 -> Wt[N][K] bf16 (tiled via LDS)
// ---------------------------------------------------------------------------
__global__ __launch_bounds__(256)
void wtrans_kernel(const float* __restrict__ w, __hip_bfloat16* __restrict__ wt,
                   int K, int N) {
  __shared__ float tile[32][33];
  const int nb = blockIdx.x * 32, kb = blockIdx.y * 32;
  const int tx = threadIdx.x & 31, ty = threadIdx.x >> 5;  // 32 x 8
#pragma unroll
  for (int i = 0; i < 4; ++i)
    tile[ty + i * 8][tx] = w[(size_t)(kb + ty + i * 8) * N + nb + tx];
  __syncthreads();
#pragma unroll
  for (int i = 0; i < 4; ++i)
    wt[(size_t)(nb + ty + i * 8) * K + kb + tx] = __float2bfloat16(tile[tx][ty + i * 8]);
}

// ---------------------------------------------------------------------------
// RoPE cos/sin tables: [576][64] each
// ---------------------------------------------------------------------------
__global__ void tables_kernel(float* __restrict__ cost, float* __restrict__ sint) {
  const int s = blockIdx.x;    // 0..575
  const int d = threadIdx.x;   // 0..63
  const int j = d >> 1;
  const float pos = (j < 16) ? (float)(s % 24) * (1.0f / 3.0f)
                             : (float)(s / 24) * (1.0f / 3.0f);
  const int fi = j & 15;
  const float freq = powf(10000.0f, -(float)fi * (1.0f / 16.0f));
  const float a = pos * freq;
  cost[s * 64 + d] = cosf(a);
  sint[s * 64 + d] = sinf(a);
}

// ---------------------------------------------------------------------------
// LayerNorm: fp32 in -> bf16 out, one block per token (1024 ch, 256 thr x 4)
// ---------------------------------------------------------------------------
__global__ __launch_bounds__(256)
void ln_kernel(const float* __restrict__ in, const float* __restrict__ g,
               const float* __restrict__ b, __hip_bfloat16* __restrict__ out) {
  const int t = blockIdx.x, tid = threadIdx.x;
  const float4 x = *(const float4*)(in + (size_t)t * 1024 + tid * 4);
  float s = x.x + x.y + x.z + x.w;
  float sq = x.x * x.x + x.y * x.y + x.z * x.z + x.w * x.w;
#pragma unroll
  for (int off = 32; off >= 1; off >>= 1) {
    s += __shfl_down(s, off);
    sq += __shfl_down(sq, off);
  }
  __shared__ float red[8];
  const int wave = tid >> 6, lane = tid & 63;
  if (lane == 0) { red[wave] = s; red[4 + wave] = sq; }
  __syncthreads();
  s = red[0] + red[1] + red[2] + red[3];
  sq = red[4] + red[5] + red[6] + red[7];
  const float mean = s * (1.0f / 1024.0f);
  const float var = sq * (1.0f / 1024.0f) - mean * mean;
  const float rstd = rsqrtf(var + 1e-6f);
  const int c = tid * 4;
  const float4 gg = *(const float4*)(g + c);
  const float4 bb = *(const float4*)(b + c);
  ushort4 o;
  o.x = bf16bits((x.x - mean) * rstd * gg.x + bb.x);
  o.y = bf16bits((x.y - mean) * rstd * gg.y + bb.y);
  o.z = bf16bits((x.z - mean) * rstd * gg.z + bb.z);
  o.w = bf16bits((x.w - mean) * rstd * gg.w + bb.w);
  *(ushort4*)((unsigned short*)out + (size_t)t * 1024 + c) = o;
}

// ---------------------------------------------------------------------------
// GEMM: C[M,N] = A[M,K] @ Bt[N,K]^T, bf16 inputs, fp32 accum.
// 128x128 tile, BK=64, 256 threads (4 waves, 2x2 of 64x64), 16x16x32 MFMA.
// Single-buffer (r0 structure: fastest measured; dbuf/8-phase were null).
// BANK-CONFLICT FIX (rule #21 pairing): LDS stays linear for global_load_lds;
// the GLOBAL source column granule (16B) is XORed with row&7, and fragment
// reads apply the same XOR: granule = ((kk>>3)+lg) ^ (lr&7). 16 lr-lanes now
// spread over 8 granule slots -> 2-way aliasing (free) instead of 16-way.
// MODE 0: out bf16 = acc + bias
// MODE 1: out bf16 = gelu(acc + bias)
// MODE 2: out f32 += acc + bias
// MODE 3: window-unpartition row perm; out f32[t] = resid[t] + acc + bias
// ---------------------------------------------------------------------------
template<int MODE>
__global__ __launch_bounds__(256)
void gemm_bt_kernel(const __hip_bfloat16* __restrict__ A,
                    const __hip_bfloat16* __restrict__ Bt,
                    const float* __restrict__ bias,
                    void* __restrict__ out,
                    const float* __restrict__ resid,
                    int M, int N, int K) {
  __shared__ __hip_bfloat16 As[128 * 64];
  __shared__ __hip_bfloat16 Bs[128 * 64];
  const int tid = threadIdx.x;
  const int wave = tid >> 6, lane = tid & 63;
  const int lr = lane & 15, lg = lane >> 4;
  // bijective XCD swizzle (m204)
  const unsigned nwg = gridDim.x * gridDim.y;
  const unsigned bid0 = blockIdx.y * gridDim.x + blockIdx.x;
  const unsigned xcd = bid0 & 7u, idx = bid0 >> 3;
  const unsigned q8 = nwg >> 3, r8 = nwg & 7u;
  const unsigned L = (xcd < r8 ? xcd * (q8 + 1u)
                               : r8 * (q8 + 1u) + (xcd - r8) * q8) + idx;
  const int bm = (int)(L / gridDim.x) * 128;
  const int bn = (int)(L % gridDim.x) * 128;
  const int wr = (wave >> 1) * 64, wc = (wave & 1) * 64;
  const int srow = lane >> 3;                       // 0..7 (LDS row mod 8)
  const int scol = ((lane & 7) ^ srow) * 8;         // pre-swizzled source col
  const int rsw = lr & 7;                           // read-side XOR key

  f32x4 acc[4][4] = {};

  for (int k0 = 0; k0 < K; k0 += 64) {
#pragma unroll
    for (int c = 0; c < 4; ++c) {
      const int ch = wave * 4 + c;
      gload16(A + (size_t)(bm + ch * 8 + srow) * K + k0 + scol, &As[ch * 512]);
      gload16(Bt + (size_t)(bn + ch * 8 + srow) * K + k0 + scol, &Bs[ch * 512]);
    }
    __syncthreads();
#pragma unroll
    for (int kk = 0; kk < 64; kk += 32) {
      const int kg = kk >> 3;  // granule base: 0 or 4
      bf16x8 af[4], bfr[4];
#pragma unroll
      for (int i = 0; i < 4; ++i)
        af[i] = *(const bf16x8*)&As[(wr + i * 16 + lr) * 64 + (((kg + lg) ^ rsw) * 8)];
#pragma unroll
      for (int i = 0; i < 4; ++i)
        bfr[i] = *(const bf16x8*)&Bs[(wc + i * 16 + lr) * 64 + (((kg + lg) ^ rsw) * 8)];
#pragma unroll
      for (int mi = 0; mi < 4; ++mi)
#pragma unroll
        for (int ni = 0; ni < 4; ++ni)
          acc[mi][ni] = __builtin_amdgcn_mfma_f32_16x16x32_bf16(af[mi], bfr[ni],
                                                                acc[mi][ni], 0, 0, 0);
    }
    __syncthreads();
  }

#pragma unroll
  for (int ni = 0; ni < 4; ++ni) {
    const int gn = bn + wc + ni * 16 + lr;
    const float bv = bias ? bias[gn] : 0.0f;
#pragma unroll
    for (int mi = 0; mi < 4; ++mi) {
      const int rowb = bm + wr + mi * 16 + lg * 4;
#pragma unroll
      for (int j = 0; j < 4; ++j) {
        const float v = acc[mi][ni][j] + bv;
        const int gm = rowb + j;
        if (MODE == 0) {
          ((__hip_bfloat16*)out)[(size_t)gm * N + gn] = __float2bfloat16(v);
        } else if (MODE == 1) {
          const float gl = 0.5f * v * (1.0f + erff(v * 0.70710678f));
          ((__hip_bfloat16*)out)[(size_t)gm * N + gn] = __float2bfloat16(gl);
        } else if (MODE == 2) {
          ((float*)out)[(size_t)gm * N + gn] += v;
        } else {
          const int win = gm / 576, s = gm % 576;
          const int bb2 = win / 9, wi = (win % 9) / 3, wj = win % 3;
          const int t = (bb2 * 72 + wi * 24 + (s / 24)) * 72 + wj * 24 + (s % 24);
          ((float*)out)[(size_t)t * 1024 + gn] =
              resid[(size_t)t * 1024 + gn] + v;
        }
      }
    }
  }
}

// ---------------------------------------------------------------------------
// RoPE + bias + window scatter for Q (pre-scaled by 0.125) and K.
// ---------------------------------------------------------------------------
__global__ __launch_bounds__(256)
void rope_kernel(const __hip_bfloat16* __restrict__ qkvraw,
                 const float* __restrict__ bq, const float* __restrict__ bk,
                 const float* __restrict__ cost, const float* __restrict__ sint,
                 __hip_bfloat16* __restrict__ qw, __hip_bfloat16* __restrict__ kw) {
  const int s = blockIdx.x;    // 0..575
  const int win = blockIdx.y;  // 0..17
  const int b = win / 9, wi = (win % 9) / 3, wj = win % 3;
  const int t = (b * 72 + wi * 24 + (s / 24)) * 72 + wj * 24 + (s % 24);
  const int tid = threadIdx.x;
  const int col = tid * 4;           // 0..1020, aligned pairs
  const int head = col >> 6, d = col & 63;
  const float c0 = cost[s * 64 + d + 0], c1 = cost[s * 64 + d + 1];
  const float c2 = cost[s * 64 + d + 2], c3 = cost[s * 64 + d + 3];
  const float s0 = sint[s * 64 + d + 0], s1 = sint[s * 64 + d + 1];
  const float s2 = sint[s * 64 + d + 2], s3 = sint[s * 64 + d + 3];
  const size_t rbase = (size_t)t * 3072;
  const size_t obase = (((size_t)(win * 16 + head)) * 576 + s) * 64 + d;
  {  // Q (fold softmax scale 1/8)
    const float q0 = __bfloat162float(qkvraw[rbase + col + 0]) + bq[col + 0];
    const float q1 = __bfloat162float(qkvraw[rbase + col + 1]) + bq[col + 1];
    const float q2 = __bfloat162float(qkvraw[rbase + col + 2]) + bq[col + 2];
    const float q3 = __bfloat162float(qkvraw[rbase + col + 3]) + bq[col + 3];
    ushort4 o;
    o.x = bf16bits(0.125f * (q0 * c0 - q1 * s0));
    o.y = bf16bits(0.125f * (q1 * c1 + q0 * s1));
    o.z = bf16bits(0.125f * (q2 * c2 - q3 * s2));
    o.w = bf16bits(0.125f * (q3 * c3 + q2 * s3));
    *(ushort4*)((unsigned short*)qw + obase) = o;
  }
  {  // K
    const float k0 = __bfloat162float(qkvraw[rbase + 1024 + col + 0]) + bk[col + 0];
    const float k1 = __bfloat162float(qkvraw[rbase + 1024 + col + 1]) + bk[col + 1];
    const float k2 = __bfloat162float(qkvraw[rbase + 1024 + col + 2]) + bk[col + 2];
    const float k3 = __bfloat162float(qkvraw[rbase + 1024 + col + 3]) + bk[col + 3];
    ushort4 o;
    o.x = bf16bits(k0 * c0 - k1 * s0);
    o.y = bf16bits(k1 * c1 + k0 * s1);
    o.z = bf16bits(k2 * c2 - k3 * s2);
    o.w = bf16bits(k3 * c3 + k2 * s3);
    *(ushort4*)((unsigned short*)kw + obase) = o;
  }
}

// ---------------------------------------------------------------------------
// V: bias + window gather + transpose: vt[win][head][d][s] bf16 (for PV MFMA)
// ---------------------------------------------------------------------------
__global__ __launch_bounds__(256)
void vtrans_kernel(const __hip_bfloat16* __restrict__ qkvraw,
                   const float* __restrict__ bv,
                   __hip_bfloat16* __restrict__ vt) {
  const int head = blockIdx.x, win = blockIdx.y;
  const int b = win / 9, wi = (win % 9) / 3, wj = win % 3;
  __shared__ __hip_bfloat16 tile[64][72];
  const int tid = threadIdx.x;
  for (int s0 = 0; s0 < 576; s0 += 64) {
#pragma unroll
    for (int rep = 0; rep < 16; ++rep) {
      const int e = rep * 256 + tid;  // 0..4095
      const int si = e >> 6, d = e & 63;
      const int s = s0 + si;
      const int t = (b * 72 + wi * 24 + (s / 24)) * 72 + wj * 24 + (s % 24);
      const float v = __bfloat162float(qkvraw[(size_t)t * 3072 + 2048 + head * 64 + d])
                    + bv[head * 64 + d];
      tile[d][si] = __float2bfloat16(v);
    }
    __syncthreads();
#pragma unroll
    for (int rep = 0; rep < 16; ++rep) {
      const int e = rep * 256 + tid;
      const int d = e >> 6, si = e & 63;
      vt[((size_t)(win * 16 + head) * 64 + d) * 576 + s0 + si] = tile[d][si];
    }
    __syncthreads();
  }
}

// ---------------------------------------------------------------------------
// Flash attention per (qtile, head, win). 256 thr = 4 waves, 16 q-rows/wave.
// K/V LDS uses the same granule-XOR swizzle as the GEMM (16-way -> 2-way).
// ---------------------------------------------------------------------------
__global__ __launch_bounds__(256)
void attn_kernel(const __hip_bfloat16* __restrict__ qw,
                 const __hip_bfloat16* __restrict__ kw,
                 const __hip_bfloat16* __restrict__ vt,
                 __hip_bfloat16* __restrict__ ow) {
  __shared__ __hip_bfloat16 Klds[2][64 * 64];
  __shared__ __hip_bfloat16 Vlds[2][64 * 64];
  __shared__ __hip_bfloat16 Plds[4 * 16 * 64];
  const unsigned nwg = gridDim.x * gridDim.y * gridDim.z;
  const unsigned bid0 = (blockIdx.z * gridDim.y + blockIdx.y) * gridDim.x + blockIdx.x;
  const unsigned Lw = (bid0 & 7u) * (nwg >> 3) + (bid0 >> 3);
  const int qt = (int)(Lw % 9u);          // 0..8
  const unsigned r = Lw / 9u;
  const int head = (int)(r & 15u);        // 0..15
  const int win = (int)(r >> 4);          // 0..17
  const int bh = win * 16 + head;
  const int tid = threadIdx.x, wave = tid >> 6, lane = tid & 63;
  const int lr = lane & 15, lg = lane >> 4;
  const int rsw = lr & 7;

  const int qrow = qt * 64 + wave * 16 + lr;
  const __hip_bfloat16* qbase = qw + ((size_t)bh * 576 + qrow) * 64;
  const bf16x8 q0 = *(const bf16x8*)(qbase + lg * 8);
  const bf16x8 q1 = *(const bf16x8*)(qbase + 32 + lg * 8);

  f32x4 oacc[4] = {};
  float mrow[4] = {-1e30f, -1e30f, -1e30f, -1e30f};
  float lrow[4] = {};

  const int srow = lane >> 3;
  const int sw = ((lane & 7) ^ srow) * 8;  // pre-swizzled source col

  auto stagekv = [&](int buf, int kv) {
#pragma unroll
    for (int c = 0; c < 2; ++c) {
      const int ch = wave * 2 + c;
      gload16(kw + ((size_t)bh * 576 + kv * 64 + ch * 8 + srow) * 64 + sw,
              &Klds[buf][ch * 512]);
      gload16(vt + ((size_t)bh * 64 + ch * 8 + srow) * 576 + kv * 64 + sw,
              &Vlds[buf][ch * 512]);
    }
  };

  stagekv(0, 0);
  __syncthreads();

  for (int kv = 0; kv < 9; ++kv) {
    const int cur = kv & 1;
    if (kv + 1 < 9) stagekv(cur ^ 1, kv + 1);
    __builtin_amdgcn_sched_barrier(0);

    f32x4 sfr[4];
#pragma unroll
    for (int c = 0; c < 4; ++c) {
      const bf16x8 b0 = *(const bf16x8*)&Klds[cur][(c * 16 + lr) * 64 + ((lg ^ rsw) * 8)];
      const bf16x8 b1 = *(const bf16x8*)&Klds[cur][(c * 16 + lr) * 64 + (((4 + lg) ^ rsw) * 8)];
      f32x4 z = {};
      z = __builtin_amdgcn_mfma_f32_16x16x32_bf16(q0, b0, z, 0, 0, 0);
      z = __builtin_amdgcn_mfma_f32_16x16x32_bf16(q1, b1, z, 0, 0, 0);
      sfr[c] = z;
    }

    float p[4][4], rscale[4];
#pragma unroll
    for (int j = 0; j < 4; ++j) {
      float mj = fmaxf(fmaxf(sfr[0][j], sfr[1][j]), fmaxf(sfr[2][j], sfr[3][j]));
#pragma unroll
      for (int off = 1; off < 16; off <<= 1) mj = fmaxf(mj, __shfl_xor(mj, off));
      const float mn = fmaxf(mrow[j], mj);
      rscale[j] = __expf(mrow[j] - mn);
      mrow[j] = mn;
      float rs = 0.0f;
#pragma unroll
      for (int c = 0; c < 4; ++c) {
        const float pp = __expf(sfr[c][j] - mn);
        p[c][j] = pp;
        rs += pp;
      }
#pragma unroll
      for (int off = 1; off < 16; off <<= 1) rs += __shfl_xor(rs, off);
      lrow[j] = lrow[j] * rscale[j] + rs;
    }
#pragma unroll
    for (int d = 0; d < 4; ++d)
#pragma unroll
      for (int j = 0; j < 4; ++j) oacc[d][j] *= rscale[j];

#pragma unroll
    for (int c = 0; c < 4; ++c)
#pragma unroll
      for (int j = 0; j < 4; ++j)
        Plds[wave * 1024 + (lg * 4 + j) * 64 + c * 16 + lr] = __float2bfloat16(p[c][j]);

    const bf16x8 pa0 = *(const bf16x8*)&Plds[wave * 1024 + lr * 64 + lg * 8];
    const bf16x8 pa1 = *(const bf16x8*)&Plds[wave * 1024 + lr * 64 + 32 + lg * 8];
#pragma unroll
    for (int d = 0; d < 4; ++d) {
      const bf16x8 v0 = *(const bf16x8*)&Vlds[cur][(d * 16 + lr) * 64 + ((lg ^ rsw) * 8)];
      const bf16x8 v1 = *(const bf16x8*)&Vlds[cur][(d * 16 + lr) * 64 + (((4 + lg) ^ rsw) * 8)];
      oacc[d] = __builtin_amdgcn_mfma_f32_16x16x32_bf16(pa0, v0, oacc[d], 0, 0, 0);
      oacc[d] = __builtin_amdgcn_mfma_f32_16x16x32_bf16(pa1, v1, oacc[d], 0, 0, 0);
    }
    __syncthreads();
  }

#pragma unroll
  for (int j = 0; j < 4; ++j) {
    const float inv = 1.0f / lrow[j];
    const int srow2 = qt * 64 + wave * 16 + lg * 4 + j;
    const size_t base = ((size_t)win * 576 + srow2) * 1024 + head * 64;
#pragma unroll
    for (int d = 0; d < 4; ++d)
      ow[base + d * 16 + lr] = __float2bfloat16(oacc[d][j] * inv);
  }
}

// ---------------------------------------------------------------------------
extern "C" void kernel_launch(void* const* d_in, const int* in_sizes, int n_in,
                              void* d_out, int out_size, void* d_ws, size_t ws_size,
                              hipStream_t stream) {
  const float* hidden = (const float*)d_in[0];
  const float* ln1_g = (const float*)d_in[1];
  const float* ln1_b = (const float*)d_in[2];
  const float* wq = (const float*)d_in[3];
  const float* bq = (const float*)d_in[4];
  const float* wk = (const float*)d_in[5];
  const float* bk = (const float*)d_in[6];
  const float* wv = (const float*)d_in[7];
  const float* bv = (const float*)d_in[8];
  const float* wo = (const float*)d_in[9];
  const float* bo = (const float*)d_in[10];
  const float* ln2_g = (const float*)d_in[11];
  const float* ln2_b = (const float*)d_in[12];
  const float* w1 = (const float*)d_in[13];
  const float* b1 = (const float*)d_in[14];
  const float* w2 = (const float*)d_in[15];
  const float* b2 = (const float*)d_in[16];
  float* out = (float*)d_out;

  char* p = (char*)d_ws;
  auto alloc = [&](size_t bytes) {
    char* r = p;
    p += (bytes + 255) & ~(size_t)255;
    return r;
  };
  __hip_bfloat16* wt_qkv = (__hip_bfloat16*)alloc(3072ull * 1024 * 2);
  __hip_bfloat16* wt_wo  = (__hip_bfloat16*)alloc(1024ull * 1024 * 2);
  __hip_bfloat16* wt_w1  = (__hip_bfloat16*)alloc(4096ull * 1024 * 2);
  __hip_bfloat16* wt_w2  = (__hip_bfloat16*)alloc(1024ull * 4096 * 2);
  float* cost = (float*)alloc(576ull * 64 * 4);
  float* sint = (float*)alloc(576ull * 64 * 4);
  __hip_bfloat16* xbuf = (__hip_bfloat16*)alloc(10368ull * 1024 * 2);  // xln / o_w / xln2
  char* big = alloc(10368ull * 4096 * 2);                              // qkvraw+qw | h1
  __hip_bfloat16* qkvraw = (__hip_bfloat16*)big;
  __hip_bfloat16* qw = (__hip_bfloat16*)(big + 10368ull * 3072 * 2);
  __hip_bfloat16* h1 = (__hip_bfloat16*)big;
  __hip_bfloat16* kw = (__hip_bfloat16*)alloc(18ull * 16 * 576 * 64 * 2);
  __hip_bfloat16* vt = (__hip_bfloat16*)alloc(18ull * 16 * 64 * 576 * 2);

  // weights -> bf16 transposed
  wtrans_kernel<<<dim3(32, 32), 256, 0, stream>>>(wq, wt_qkv, 1024, 1024);
  wtrans_kernel<<<dim3(32, 32), 256, 0, stream>>>(wk, wt_qkv + 1024ull * 1024, 1024, 1024);
  wtrans_kernel<<<dim3(32, 32), 256, 0, stream>>>(wv, wt_qkv + 2048ull * 1024, 1024, 1024);
  wtrans_kernel<<<dim3(32, 32), 256, 0, stream>>>(wo, wt_wo, 1024, 1024);
  wtrans_kernel<<<dim3(128, 32), 256, 0, stream>>>(w1, wt_w1, 1024, 4096);
  wtrans_kernel<<<dim3(32, 128), 256, 0, stream>>>(w2, wt_w2, 4096, 1024);
  tables_kernel<<<576, 64, 0, stream>>>(cost, sint);

  // LN1 -> xln (bf16)
  ln_kernel<<<10368, 256, 0, stream>>>(hidden, ln1_g, ln1_b, xbuf);
  // QKV fused GEMM: [10368,1024] x [3072,1024]^T -> qkvraw bf16
  gemm_bt_kernel<0><<<dim3(24, 81), 256, 0, stream>>>(
      xbuf, wt_qkv, nullptr, qkvraw, nullptr, 10368, 3072, 1024);
  // RoPE + window scatter (q scaled by 0.125); V bias + transpose
  rope_kernel<<<dim3(576, 18), 256, 0, stream>>>(qkvraw, bq, bk, cost, sint, qw, kw);
  vtrans_kernel<<<dim3(16, 18), 256, 0, stream>>>(qkvraw, bv, vt);
  // attention -> o_w (windowed rows, [tw][1024]) into xbuf
  attn_kernel<<<dim3(9, 16, 18), 256, 0, stream>>>(qw, kw, vt, xbuf);
  // Wo GEMM + bias + residual + window-unpartition -> d_out (fp32 x)
  gemm_bt_kernel<3><<<dim3(8, 81), 256, 0, stream>>>(
      xbuf, wt_wo, bo, out, hidden, 10368, 1024, 1024);
  // LN2 -> xln2 (bf16)
  ln_kernel<<<10368, 256, 0, stream>>>(out, ln2_g, ln2_b, xbuf);
  // MLP up + GELU -> h1 bf16
  gemm_bt_kernel<1><<<dim3(32, 81), 256, 0, stream>>>(
      xbuf, wt_w1, b1, h1, nullptr, 10368, 4096, 1024);
  // MLP down, += into d_out
  gemm_bt_kernel<2><<<dim3(8, 81), 256, 0, stream>>>(
      h1, wt_w2, b2, out, nullptr, 10368, 1024, 4096);
}